// Round 8
// baseline (273.889 us; speedup 1.0000x reference)
//
#include <hip/hip_runtime.h>

// Problem constants
#define B_  2
#define S_  2048
#define D_  1024
#define H_  16
#define HD_ 64
#define M_  (B_*S_)   // 4096

typedef __attribute__((ext_vector_type(8))) short  short8;   // 8 bf16 (4 VGPRs)
typedef __attribute__((ext_vector_type(4))) float  float4v;  // 4 fp32
typedef __attribute__((ext_vector_type(4))) int    int4v;    // 16B
typedef __attribute__((ext_vector_type(4))) unsigned short ushort4v; // 8B

// 1/sqrt(D) * log2(e) folded together: softmax uses exp2 (v_exp_f32 native)
#define PSCALE 0.0450843341f   // (1/32) * 1.4426950408889634

__device__ __forceinline__ unsigned int pack2_bf16(float a, float b) {
#if __has_builtin(__builtin_amdgcn_cvt_pk_bf16_f32)
    auto p = __builtin_amdgcn_cvt_pk_bf16_f32(a, b);   // 1 VALU op, RNE
    return __builtin_bit_cast(unsigned int, p);
#else
    unsigned int xa = __builtin_bit_cast(unsigned int, a);
    unsigned int xb = __builtin_bit_cast(unsigned int, b);
    xa += 0x7fffu + ((xa >> 16) & 1u);
    xb += 0x7fffu + ((xb >> 16) & 1u);
    return (xa >> 16) | (xb & 0xffff0000u);
#endif
}
__device__ __forceinline__ unsigned short f_to_bf16bits(float f) {
#if __has_builtin(__builtin_amdgcn_cvt_pk_bf16_f32)
    return (unsigned short)(pack2_bf16(f, f) & 0xffffu);
#else
    unsigned int x = __builtin_bit_cast(unsigned int, f);
    x += 0x7fffu + ((x >> 16) & 1u);
    return (unsigned short)(x >> 16);
#endif
}

__device__ __forceinline__ float fast_exp2(float x) {
#if __has_builtin(__builtin_amdgcn_exp2f)
    return __builtin_amdgcn_exp2f(x);
#else
    return exp2f(x);
#endif
}

// ---------------------------------------------------------------------------
// fp32 -> bf16 bulk convert: X(4M) + Wq,Wk,Wv,Wo (1M each). 8 elems/thread.
// ---------------------------------------------------------------------------
__global__ __launch_bounds__(256) void cvt_bf16(
    const float* __restrict__ X,  const float* __restrict__ Wq,
    const float* __restrict__ Wk, const float* __restrict__ Wv,
    const float* __restrict__ Wo,
    unsigned short* __restrict__ Xb,  unsigned short* __restrict__ Wqb,
    unsigned short* __restrict__ Wkb, unsigned short* __restrict__ Wvb,
    unsigned short* __restrict__ Wob)
{
    const long t = (long)blockIdx.x * 256 + threadIdx.x;
    const long e = t * 8;
    const float* src; unsigned short* dst; long off;
    if      (e < 4194304) { src = X;  dst = Xb;  off = e; }
    else if (e < 5242880) { src = Wq; dst = Wqb; off = e - 4194304; }
    else if (e < 6291456) { src = Wk; dst = Wkb; off = e - 5242880; }
    else if (e < 7340032) { src = Wv; dst = Wvb; off = e - 6291456; }
    else                  { src = Wo; dst = Wob; off = e - 7340032; }
    float4v a = *(const float4v*)&src[off];
    float4v b = *(const float4v*)&src[off + 4];
    int4v o;
    o[0] = (int)pack2_bf16(a[0], a[1]);
    o[1] = (int)pack2_bf16(a[2], a[3]);
    o[2] = (int)pack2_bf16(b[0], b[1]);
    o[3] = (int)pack2_bf16(b[2], b[3]);
    *(int4v*)&dst[off] = o;
}

// ---------------------------------------------------------------------------
// NT GEMM, BK=64, distance-1 register prefetch (next tile's global loads
// issue after the compute barrier, consumed at next iter's ds_write).
// mode 0: Q  out[((b*H+h)*S+s)*HD+hd] * PSCALE  (exp2-folded softmax scale)
// mode 1: K  same layout, unscaled
// mode 2: Vt out[((b*H+h)*HD+hd)*S+s] -- operands SWAPPED (A=Wv, B=X)
// mode 3: fp32 row-major out[m*D+n]
// ---------------------------------------------------------------------------
__global__ __launch_bounds__(256) void gemm_bt(
    const unsigned short* __restrict__ A,
    const unsigned short* __restrict__ B0,
    const unsigned short* __restrict__ B1,
    const unsigned short* __restrict__ B2,
    void* __restrict__ O0, void* __restrict__ O1, void* __restrict__ O2,
    int mode_base)
{
    const int K = 1024;
    const int z = blockIdx.z;
    const int mode = mode_base + z;
    const unsigned short* Aop;
    const unsigned short* Bop;
    void* Op = (z == 0) ? O0 : (z == 1) ? O1 : O2;
    int m0, n0;
    if (mode == 2) {            // swapped: A=Wv (rows=out-dim), B=X (rows=s)
        Aop = B2; Bop = A;
        m0 = blockIdx.y * 128;
        n0 = blockIdx.x * 128;
    } else {
        Aop = A;
        Bop = (z == 0) ? B0 : (z == 1) ? B1 : B2;
        m0 = blockIdx.x * 128;
        n0 = blockIdx.y * 128;
    }

    __shared__ alignas(16) unsigned short As[128 * 64];   // 16 KB
    __shared__ alignas(16) unsigned short Bs[128 * 64];   // 16 KB

    const int tid  = threadIdx.x;
    const int wv   = tid >> 6;
    const int lane = tid & 63;
    const int wm   = wv >> 1, wn = wv & 1;
    const int q4   = lane >> 4, l15 = lane & 15;

    const unsigned short* gA[4];
    const unsigned short* gB[4];
    int ldsoff[4];
#pragma unroll
    for (int j = 0; j < 4; j++) {
        const int r = wv * 32 + j * 8 + (lane >> 3);
        const int c = (((lane & 7) ^ (r & 7)) * 8);
        gA[j] = Aop + (long)(m0 + r) * K + c;
        gB[j] = Bop + (long)(n0 + r) * K + c;
        ldsoff[j] = (wv * 32 + j * 8) * 64 + lane * 8;   // phys chunk = lane&7
    }

    int aoff[2][4], boff[2][4];
#pragma unroll
    for (int ks = 0; ks < 2; ks++)
#pragma unroll
        for (int t = 0; t < 4; t++) {
            const int swz = (((ks * 4 + q4) ^ (l15 & 7)) * 8);
            aoff[ks][t] = (wm * 64 + t * 16 + l15) * 64 + swz;
            boff[ks][t] = (wn * 64 + t * 16 + l15) * 64 + swz;
        }

    float4v acc[4][4];
#pragma unroll
    for (int i = 0; i < 4; i++)
#pragma unroll
        for (int j = 0; j < 4; j++) acc[i][j] = (float4v)0.0f;

    int4v ar[4], br[4];
#pragma unroll
    for (int j = 0; j < 4; j++) {
        ar[j] = *(const int4v*)gA[j];
        br[j] = *(const int4v*)gB[j];
        gA[j] += 64; gB[j] += 64;
    }

    for (int k0 = 0; k0 < K; k0 += 64) {
        __syncthreads();
#pragma unroll
        for (int j = 0; j < 4; j++) {
            *(int4v*)&As[ldsoff[j]] = ar[j];
            *(int4v*)&Bs[ldsoff[j]] = br[j];
        }
        __syncthreads();

        if (k0 + 64 < K) {
#pragma unroll
            for (int j = 0; j < 4; j++) {
                ar[j] = *(const int4v*)gA[j];
                br[j] = *(const int4v*)gB[j];
                gA[j] += 64; gB[j] += 64;
            }
        }

#pragma unroll
        for (int ks = 0; ks < 2; ks++) {
            short8 afr[4], bfr[4];
#pragma unroll
            for (int mt = 0; mt < 4; mt++) afr[mt] = *(const short8*)&As[aoff[ks][mt]];
#pragma unroll
            for (int nt = 0; nt < 4; nt++) bfr[nt] = *(const short8*)&Bs[boff[ks][nt]];
#pragma unroll
            for (int mt = 0; mt < 4; mt++)
#pragma unroll
                for (int nt = 0; nt < 4; nt++)
                    acc[mt][nt] = __builtin_amdgcn_mfma_f32_16x16x32_bf16(
                        afr[mt], bfr[nt], acc[mt][nt], 0, 0, 0);
        }
    }

#pragma unroll
    for (int mt = 0; mt < 4; mt++)
#pragma unroll
        for (int nt = 0; nt < 4; nt++)
#pragma unroll
            for (int r = 0; r < 4; r++) {
                const int m = m0 + wm * 64 + mt * 16 + q4 * 4 + r;
                const int n = n0 + wn * 64 + nt * 16 + l15;
                float v = acc[mt][nt][r];
                if (mode == 3) {
                    ((float*)Op)[(long)m * D_ + n] = v;
                } else if (mode == 2) {
                    const long off = (((long)(n >> 11) * H_ + (m >> 6)) * HD_ + (m & 63)) * S_ + (n & 2047);
                    ((unsigned short*)Op)[off] = f_to_bf16bits(v);
                } else {
                    const long off = ((long)((m >> 11) * H_ + (n >> 6)) * S_ + (m & 2047)) * HD_ + (n & 63);
                    if (mode == 0) v *= PSCALE;
                    ((unsigned short*)Op)[off] = f_to_bf16bits(v);
                }
            }
}

// ---------------------------------------------------------------------------
// Flash attention (no online-max; scores bounded, exp can't overflow fp32;
// normalization divides out constants). 256 thr / 4 waves, BK=128 staging:
// stage K(128x64)+Vt(64x128) once, then TWO barrier-free 64-col compute
// halves (Ps is wave-private, reused). 16 iterations, 32 MFMA/barrier-pair.
// LDS 40KB -> exactly 4 WG/CU (= grid/CU). Zero-conflict XOR swizzles.
// ---------------------------------------------------------------------------
__global__ __launch_bounds__(256) void attn(
    const unsigned short* __restrict__ Q,    // [B,H,S,HD], pre-scaled by PSCALE
    const unsigned short* __restrict__ Kk,   // [B,H,S,HD]
    const unsigned short* __restrict__ Vt,   // [B,H,HD,S]
    const float* __restrict__ mask,          // [S,S]
    unsigned short* __restrict__ ctx)        // [B,S,D]
{
    __shared__ alignas(16) unsigned short Ks[128 * 64];   // [k][d]  16 KB
    __shared__ alignas(16) unsigned short Vs[64 * 128];   // [d][k]  16 KB
    __shared__ alignas(16) unsigned short Ps[4][16 * 64]; //          8 KB

    const int tid  = threadIdx.x;
    const int wv   = tid >> 6;
    const int lane = tid & 63;
    const int q4   = lane >> 4, l15 = lane & 15;
    const int bh   = blockIdx.x;
    const int q0   = blockIdx.y * 64;

    const long head = (long)bh * S_ * HD_;

    const int qrow = q0 + wv * 16 + l15;
    short8 qfr[2];
    qfr[0] = *(const short8*)&Q[head + (long)qrow * HD_ + q4 * 8];
    qfr[1] = *(const short8*)&Q[head + (long)qrow * HD_ + 32 + q4 * 8];

    float l_acc[4];
#pragma unroll
    for (int r = 0; r < 4; r++) l_acc[r] = 0.0f;
    float4v oacc[4];
#pragma unroll
    for (int dt = 0; dt < 4; dt++) oacc[dt] = (float4v)0.0f;

    // K staging: 128 rows x 64 cols; inst j covers rows j*32 + tid/8;
    // phys chunk = tid&7, logical = phys ^ (row&7)
    const int krow = tid >> 3, ksch = tid & 7;
    const unsigned short* gK[4];
    int kldso[4];
#pragma unroll
    for (int j = 0; j < 4; j++) {
        const int row = j * 32 + krow;
        gK[j] = Kk + head + (long)row * HD_ + ((ksch ^ (row & 7)) * 8);
        kldso[j] = row * 64 + ksch * 8;
    }
    // V staging: 64 rows x 128 cols; inst j covers rows j*16 + tid/16;
    // logical chunk l = tid&15, phys = (l&8) | ((l&7) ^ (row&7))
    const int vrow = tid >> 4, vl = tid & 15;
    const unsigned short* gV[4];
    int vldso[4];
#pragma unroll
    for (int j = 0; j < 4; j++) {
        const int row = j * 16 + vrow;
        gV[j] = Vt + head + (long)row * S_ + vl * 8;
        vldso[j] = row * 128 + (((vl & 8) | ((vl & 7) ^ (row & 7))) * 8);
    }

    // per-thread mask row bases
    const float* mrow[4];
#pragma unroll
    for (int r = 0; r < 4; r++)
        mrow[r] = mask + (long)(q0 + wv * 16 + q4 * 4 + r) * S_ + l15;

    // mask for first 64-col half into registers
    float mv[4][4];
#pragma unroll
    for (int nt = 0; nt < 4; nt++)
#pragma unroll
        for (int r = 0; r < 4; r++) mv[nt][r] = mrow[r][nt * 16];

    const int pswz = (q4 & 1) * 4;
    const int psl3 = l15 >> 3;
    const int kp0 = ((q4       ^ (l15 & 7)) * 8);   // QK/P chunk offsets
    const int kp1 = (((4 + q4) ^ (l15 & 7)) * 8);   // (loop-invariant)

    for (int k0 = 0; k0 < S_; k0 += 128) {
        __syncthreads();   // prior iter's LDS reads done (WAR)
#pragma unroll
        for (int j = 0; j < 4; j++)
            *(int4v*)&Ks[kldso[j]] = *(const int4v*)(gK[j] + (long)k0 * HD_);
#pragma unroll
        for (int j = 0; j < 4; j++)
            *(int4v*)&Vs[vldso[j]] = *(const int4v*)(gV[j] + k0);
        __syncthreads();

#pragma unroll
        for (int h = 0; h < 2; h++) {
            const int kb = k0 + h * 64;

            // QK^T on rows h*64 .. h*64+63 of the K tile
            float4v sfr[4];
#pragma unroll
            for (int nt = 0; nt < 4; nt++) {
                const int row = h * 64 + nt * 16 + l15;
                short8 kb0 = *(const short8*)&Ks[row * 64 + kp0];
                short8 kb1 = *(const short8*)&Ks[row * 64 + kp1];
                float4v s = (float4v)0.0f;
                s = __builtin_amdgcn_mfma_f32_16x16x32_bf16(qfr[0], kb0, s, 0, 0, 0);
                s = __builtin_amdgcn_mfma_f32_16x16x32_bf16(qfr[1], kb1, s, 0, 0, 0);
                sfr[nt] = s;
            }

            // mask prefetch for next 64-col half
            float mvn[4][4];
            const int knext = (kb + 64 < S_) ? kb + 64 : kb;
#pragma unroll
            for (int nt = 0; nt < 4; nt++)
#pragma unroll
                for (int r = 0; r < 4; r++) mvn[nt][r] = mrow[r][knext + nt * 16];

            // p = 2^(dot_scaled + mask*PSCALE); per-lane row sums; P -> LDS
#pragma unroll
            for (int nt = 0; nt < 4; nt++)
#pragma unroll
                for (int r = 0; r < 4; r++) {
                    const float p = fast_exp2(fmaf(mv[nt][r], PSCALE, sfr[nt][r]));
                    l_acc[r] += p;
                    const int c8 = (nt * 2 + psl3) ^ (pswz + r);
                    Ps[wv][(q4 * 4 + r) * 64 + c8 * 8 + (l15 & 7)] = f_to_bf16bits(p);
                }

            short8 pf0 = *(const short8*)&Ps[wv][l15 * 64 + kp0];
            short8 pf1 = *(const short8*)&Ps[wv][l15 * 64 + kp1];

            // O += P V  (V chunks h*8 + {q4, 4+q4} logical)
#pragma unroll
            for (int dt = 0; dt < 4; dt++) {
                const int row = dt * 16 + l15;
                short8 vb0 = *(const short8*)&Vs[row * 128 + h * 64 + kp0];
                short8 vb1 = *(const short8*)&Vs[row * 128 + h * 64 + kp1];
                float4v o = oacc[dt];
                o = __builtin_amdgcn_mfma_f32_16x16x32_bf16(pf0, vb0, o, 0, 0, 0);
                o = __builtin_amdgcn_mfma_f32_16x16x32_bf16(pf1, vb1, o, 0, 0, 0);
                oacc[dt] = o;
            }

#pragma unroll
            for (int nt = 0; nt < 4; nt++)
#pragma unroll
                for (int r = 0; r < 4; r++) mv[nt][r] = mvn[nt][r];
        }
    }

    // single end-of-loop butterfly over the 16 column-lanes
#pragma unroll
    for (int r = 0; r < 4; r++) {
#pragma unroll
        for (int off = 1; off < 16; off <<= 1)
            l_acc[r] += __shfl_xor(l_acc[r], off);
    }

    const int b = bh >> 4, h = bh & 15;
#pragma unroll
    for (int dt = 0; dt < 4; dt++)
#pragma unroll
        for (int r = 0; r < 4; r++) {
            const int qg = q0 + wv * 16 + q4 * 4 + r;
            const int d  = dt * 16 + l15;
            const float v = oacc[dt][r] / l_acc[r];
            ctx[((long)(b * S_ + qg)) * D_ + h * HD_ + d] = f_to_bf16bits(v);
        }
}

extern "C" void kernel_launch(void* const* d_in, const int* in_sizes, int n_in,
                              void* d_out, int out_size, void* d_ws, size_t ws_size,
                              hipStream_t stream) {
    const float* X    = (const float*)d_in[0];
    const float* mask = (const float*)d_in[1];
    const float* Wq   = (const float*)d_in[2];
    const float* Wk   = (const float*)d_in[3];
    const float* Wv   = (const float*)d_in[4];
    const float* Wo   = (const float*)d_in[5];
    float* out        = (float*)d_out;

    unsigned short* ws = (unsigned short*)d_ws;
    unsigned short* qws  = ws;                 // 4M elems each
    unsigned short* kws  = ws + 4194304;
    unsigned short* vtws = ws + 8388608;
    unsigned short* ctx  = ws + 12582912;
    unsigned short* Xb   = ws + 16777216;      // 4M
    unsigned short* Wqb  = ws + 20971520;      // 1M each
    unsigned short* Wkb  = ws + 22020096;
    unsigned short* Wvb  = ws + 23068672;
    unsigned short* Wob  = ws + 24117248;      // end = 48MB

    cvt_bf16<<<dim3(4096), 256, 0, stream>>>(X, Wq, Wk, Wv, Wo, Xb, Wqb, Wkb, Wvb, Wob);
    gemm_bt<<<dim3(32, 8, 3), 256, 0, stream>>>(Xb, Wqb, Wkb, Wvb, qws, kws, vtws, 0);
    attn<<<dim3(32, 32, 1), 256, 0, stream>>>(qws, kws, vtws, mask, ctx);
    gemm_bt<<<dim3(32, 8, 1), 256, 0, stream>>>(ctx, Wob, Wob, Wob, out, out, out, 3);
}

// Round 9
// 239.117 us; speedup vs baseline: 1.1454x; 1.1454x over previous
//
#include <hip/hip_runtime.h>

// Problem constants
#define B_  2
#define S_  2048
#define D_  1024
#define H_  16
#define HD_ 64
#define M_  (B_*S_)   // 4096

typedef __attribute__((ext_vector_type(8))) short  short8;   // 8 bf16 (4 VGPRs)
typedef __attribute__((ext_vector_type(4))) float  float4v;  // 4 fp32
typedef __attribute__((ext_vector_type(4))) int    int4v;    // 16B
typedef __attribute__((ext_vector_type(4))) unsigned short ushort4v; // 8B

// 1/sqrt(D) * log2(e): softmax via native exp2 (v_exp_f32)
#define PSCALE 0.0450843341f   // (1/32) * 1.4426950408889634

__device__ __forceinline__ unsigned int pack2_bf16(float a, float b) {
#if __has_builtin(__builtin_amdgcn_cvt_pk_bf16_f32)
    auto p = __builtin_amdgcn_cvt_pk_bf16_f32(a, b);   // 1 VALU op, RNE
    return __builtin_bit_cast(unsigned int, p);
#else
    unsigned int xa = __builtin_bit_cast(unsigned int, a);
    unsigned int xb = __builtin_bit_cast(unsigned int, b);
    xa += 0x7fffu + ((xa >> 16) & 1u);
    xb += 0x7fffu + ((xb >> 16) & 1u);
    return (xa >> 16) | (xb & 0xffff0000u);
#endif
}
__device__ __forceinline__ unsigned short f_to_bf16bits(float f) {
#if __has_builtin(__builtin_amdgcn_cvt_pk_bf16_f32)
    return (unsigned short)(pack2_bf16(f, f) & 0xffffu);
#else
    unsigned int x = __builtin_bit_cast(unsigned int, f);
    x += 0x7fffu + ((x >> 16) & 1u);
    return (unsigned short)(x >> 16);
#endif
}

__device__ __forceinline__ float fast_exp2(float x) {
#if __has_builtin(__builtin_amdgcn_exp2f)
    return __builtin_amdgcn_exp2f(x);
#else
    return exp2f(x);
#endif
}

// ---------------------------------------------------------------------------
// fp32 -> bf16 bulk convert: X(4M) + Wq,Wk,Wv,Wo (1M each). 8 elems/thread.
// ---------------------------------------------------------------------------
__global__ __launch_bounds__(256) void cvt_bf16(
    const float* __restrict__ X,  const float* __restrict__ Wq,
    const float* __restrict__ Wk, const float* __restrict__ Wv,
    const float* __restrict__ Wo,
    unsigned short* __restrict__ Xb,  unsigned short* __restrict__ Wqb,
    unsigned short* __restrict__ Wkb, unsigned short* __restrict__ Wvb,
    unsigned short* __restrict__ Wob)
{
    const long t = (long)blockIdx.x * 256 + threadIdx.x;
    const long e = t * 8;
    const float* src; unsigned short* dst; long off;
    if      (e < 4194304) { src = X;  dst = Xb;  off = e; }
    else if (e < 5242880) { src = Wq; dst = Wqb; off = e - 4194304; }
    else if (e < 6291456) { src = Wk; dst = Wkb; off = e - 5242880; }
    else if (e < 7340032) { src = Wv; dst = Wvb; off = e - 6291456; }
    else                  { src = Wo; dst = Wob; off = e - 7340032; }
    float4v a = *(const float4v*)&src[off];
    float4v b = *(const float4v*)&src[off + 4];
    int4v o;
    o[0] = (int)pack2_bf16(a[0], a[1]);
    o[1] = (int)pack2_bf16(a[2], a[3]);
    o[2] = (int)pack2_bf16(b[0], b[1]);
    o[3] = (int)pack2_bf16(b[2], b[3]);
    *(int4v*)&dst[off] = o;
}

// ---------------------------------------------------------------------------
// NT GEMM, BK=64, distance-1 register prefetch (R7 variant, best measured).
// mode 0: Q  out[((b*H+h)*S+s)*HD+hd] * PSCALE  (exp2-folded softmax scale)
// mode 1: K  same layout, unscaled
// mode 2: Vt out[((b*H+h)*HD+hd)*S+s] -- operands SWAPPED (A=Wv, B=X)
// mode 3: fp32 row-major out[m*D+n]
// ---------------------------------------------------------------------------
__global__ __launch_bounds__(256) void gemm_bt(
    const unsigned short* __restrict__ A,
    const unsigned short* __restrict__ B0,
    const unsigned short* __restrict__ B1,
    const unsigned short* __restrict__ B2,
    void* __restrict__ O0, void* __restrict__ O1, void* __restrict__ O2,
    int mode_base)
{
    const int K = 1024;
    const int z = blockIdx.z;
    const int mode = mode_base + z;
    const unsigned short* Aop;
    const unsigned short* Bop;
    void* Op = (z == 0) ? O0 : (z == 1) ? O1 : O2;
    int m0, n0;
    if (mode == 2) {            // swapped: A=Wv (rows=out-dim), B=X (rows=s)
        Aop = B2; Bop = A;
        m0 = blockIdx.y * 128;
        n0 = blockIdx.x * 128;
    } else {
        Aop = A;
        Bop = (z == 0) ? B0 : (z == 1) ? B1 : B2;
        m0 = blockIdx.x * 128;
        n0 = blockIdx.y * 128;
    }

    __shared__ alignas(16) unsigned short As[128 * 64];   // 16 KB
    __shared__ alignas(16) unsigned short Bs[128 * 64];   // 16 KB

    const int tid  = threadIdx.x;
    const int wv   = tid >> 6;
    const int lane = tid & 63;
    const int wm   = wv >> 1, wn = wv & 1;
    const int q4   = lane >> 4, l15 = lane & 15;

    const unsigned short* gA[4];
    const unsigned short* gB[4];
    int ldsoff[4];
#pragma unroll
    for (int j = 0; j < 4; j++) {
        const int r = wv * 32 + j * 8 + (lane >> 3);
        const int c = (((lane & 7) ^ (r & 7)) * 8);
        gA[j] = Aop + (long)(m0 + r) * K + c;
        gB[j] = Bop + (long)(n0 + r) * K + c;
        ldsoff[j] = (wv * 32 + j * 8) * 64 + lane * 8;   // phys chunk = lane&7
    }

    int aoff[2][4], boff[2][4];
#pragma unroll
    for (int ks = 0; ks < 2; ks++)
#pragma unroll
        for (int t = 0; t < 4; t++) {
            const int swz = (((ks * 4 + q4) ^ (l15 & 7)) * 8);
            aoff[ks][t] = (wm * 64 + t * 16 + l15) * 64 + swz;
            boff[ks][t] = (wn * 64 + t * 16 + l15) * 64 + swz;
        }

    float4v acc[4][4];
#pragma unroll
    for (int i = 0; i < 4; i++)
#pragma unroll
        for (int j = 0; j < 4; j++) acc[i][j] = (float4v)0.0f;

    int4v ar[4], br[4];
#pragma unroll
    for (int j = 0; j < 4; j++) {
        ar[j] = *(const int4v*)gA[j];
        br[j] = *(const int4v*)gB[j];
        gA[j] += 64; gB[j] += 64;
    }

    for (int k0 = 0; k0 < K; k0 += 64) {
        __syncthreads();
#pragma unroll
        for (int j = 0; j < 4; j++) {
            *(int4v*)&As[ldsoff[j]] = ar[j];
            *(int4v*)&Bs[ldsoff[j]] = br[j];
        }
        __syncthreads();

        if (k0 + 64 < K) {
#pragma unroll
            for (int j = 0; j < 4; j++) {
                ar[j] = *(const int4v*)gA[j];
                br[j] = *(const int4v*)gB[j];
                gA[j] += 64; gB[j] += 64;
            }
        }

#pragma unroll
        for (int ks = 0; ks < 2; ks++) {
            short8 afr[4], bfr[4];
#pragma unroll
            for (int mt = 0; mt < 4; mt++) afr[mt] = *(const short8*)&As[aoff[ks][mt]];
#pragma unroll
            for (int nt = 0; nt < 4; nt++) bfr[nt] = *(const short8*)&Bs[boff[ks][nt]];
#pragma unroll
            for (int mt = 0; mt < 4; mt++)
#pragma unroll
                for (int nt = 0; nt < 4; nt++)
                    acc[mt][nt] = __builtin_amdgcn_mfma_f32_16x16x32_bf16(
                        afr[mt], bfr[nt], acc[mt][nt], 0, 0, 0);
        }
    }

#pragma unroll
    for (int mt = 0; mt < 4; mt++)
#pragma unroll
        for (int nt = 0; nt < 4; nt++)
#pragma unroll
            for (int r = 0; r < 4; r++) {
                const int m = m0 + wm * 64 + mt * 16 + q4 * 4 + r;
                const int n = n0 + wn * 64 + nt * 16 + l15;
                float v = acc[mt][nt][r];
                if (mode == 3) {
                    ((float*)Op)[(long)m * D_ + n] = v;
                } else if (mode == 2) {
                    const long off = (((long)(n >> 11) * H_ + (m >> 6)) * HD_ + (m & 63)) * S_ + (n & 2047);
                    ((unsigned short*)Op)[off] = f_to_bf16bits(v);
                } else {
                    const long off = ((long)((m >> 11) * H_ + (n >> 6)) * S_ + (m & 2047)) * HD_ + (n & 63);
                    if (mode == 0) v *= PSCALE;
                    ((unsigned short*)Op)[off] = f_to_bf16bits(v);
                }
            }
}

// ---------------------------------------------------------------------------
// Flash attention — EXACT R3 structure (best measured: 89.4 us), with two
// pure-VALU cuts: native exp2 (PSCALE fold) and 1-op bf16 cvt. No address,
// layout, or pipeline changes. 256 thr / 4 waves, in-loop staging, padded
// LDS (x72), mask register prefetch. Grid: x = q-block, y = bh.
// No online-max: scores bounded, exp2 can't overflow fp32; normalization
// divides out any constant.
// ---------------------------------------------------------------------------
__global__ __launch_bounds__(256) void attn(
    const unsigned short* __restrict__ Q,    // [B,H,S,HD], pre-scaled by PSCALE
    const unsigned short* __restrict__ Kk,   // [B,H,S,HD]
    const unsigned short* __restrict__ Vt,   // [B,H,HD,S]
    const float* __restrict__ mask,          // [S,S]
    unsigned short* __restrict__ ctx)        // [B,S,D]
{
    __shared__ alignas(16) unsigned short Ks [64 * 72];      // [k_local][d], +8 pad
    __shared__ alignas(16) unsigned short Vts[64 * 72];      // [d][k_local]
    __shared__ alignas(16) unsigned short Ps [4][16 * 72];   // per-wave P [q][k]

    const int tid  = threadIdx.x;
    const int wv   = tid >> 6;
    const int lane = tid & 63;
    const int q4   = lane >> 4, l15 = lane & 15;
    const int bh   = blockIdx.y;
    const int q0   = blockIdx.x * 64;

    const long head = (long)bh * S_ * HD_;

    const int qrow = q0 + wv * 16 + l15;
    short8 qfr[2];
    qfr[0] = *(const short8*)&Q[head + (long)qrow * HD_ + q4 * 8];
    qfr[1] = *(const short8*)&Q[head + (long)qrow * HD_ + 32 + q4 * 8];

    float l_acc[4];
#pragma unroll
    for (int r = 0; r < 4; r++) l_acc[r] = 0.0f;
    float4v oacc[4];
#pragma unroll
    for (int dt = 0; dt < 4; dt++) oacc[dt] = (float4v)0.0f;

    const int lrow = tid >> 3;        // 0..31
    const int lcol = (tid & 7) * 8;   // 0..56

    // per-thread mask row bases
    const float* mrow[4];
#pragma unroll
    for (int r = 0; r < 4; r++)
        mrow[r] = mask + (long)(q0 + wv * 16 + q4 * 4 + r) * S_ + l15;

    // mask for iter 0 into registers
    float mv[4][4];
#pragma unroll
    for (int nt = 0; nt < 4; nt++)
#pragma unroll
        for (int r = 0; r < 4; r++) mv[nt][r] = mrow[r][nt * 16];

    for (int k0 = 0; k0 < S_; k0 += 64) {
        __syncthreads();
        *(int4v*)&Ks [lrow * 72 + lcol]        = *(const int4v*)&Kk[head + (long)(k0 + lrow)      * HD_ + lcol];
        *(int4v*)&Ks [(lrow + 32) * 72 + lcol] = *(const int4v*)&Kk[head + (long)(k0 + lrow + 32) * HD_ + lcol];
        *(int4v*)&Vts[lrow * 72 + lcol]        = *(const int4v*)&Vt[head + (long)lrow        * S_ + k0 + lcol];
        *(int4v*)&Vts[(lrow + 32) * 72 + lcol] = *(const int4v*)&Vt[head + (long)(lrow + 32) * S_ + k0 + lcol];
        __syncthreads();

        float4v sfr[4];
#pragma unroll
        for (int nt = 0; nt < 4; nt++) {
            short8 kb0 = *(const short8*)&Ks[(nt * 16 + l15) * 72 + q4 * 8];
            short8 kb1 = *(const short8*)&Ks[(nt * 16 + l15) * 72 + 32 + q4 * 8];
            float4v s = (float4v)0.0f;
            s = __builtin_amdgcn_mfma_f32_16x16x32_bf16(qfr[0], kb0, s, 0, 0, 0);
            s = __builtin_amdgcn_mfma_f32_16x16x32_bf16(qfr[1], kb1, s, 0, 0, 0);
            sfr[nt] = s;
        }

        // mask prefetch for next iteration
        float mvn[4][4];
        const int knext = (k0 + 64 < S_) ? k0 + 64 : k0;
#pragma unroll
        for (int nt = 0; nt < 4; nt++)
#pragma unroll
            for (int r = 0; r < 4; r++) mvn[nt][r] = mrow[r][knext + nt * 16];

        // p = 2^(dot_scaled + mask*PSCALE); per-lane row sums; P -> LDS
#pragma unroll
        for (int nt = 0; nt < 4; nt++)
#pragma unroll
            for (int r = 0; r < 4; r++) {
                const float p = fast_exp2(fmaf(mv[nt][r], PSCALE, sfr[nt][r]));
                l_acc[r] += p;
                Ps[wv][(q4 * 4 + r) * 72 + nt * 16 + l15] = f_to_bf16bits(p);
            }

        short8 pf0 = *(const short8*)&Ps[wv][l15 * 72 + q4 * 8];
        short8 pf1 = *(const short8*)&Ps[wv][l15 * 72 + 32 + q4 * 8];

#pragma unroll
        for (int dt = 0; dt < 4; dt++) {
            short8 vb0 = *(const short8*)&Vts[(dt * 16 + l15) * 72 + q4 * 8];
            short8 vb1 = *(const short8*)&Vts[(dt * 16 + l15) * 72 + 32 + q4 * 8];
            float4v o = oacc[dt];
            o = __builtin_amdgcn_mfma_f32_16x16x32_bf16(pf0, vb0, o, 0, 0, 0);
            o = __builtin_amdgcn_mfma_f32_16x16x32_bf16(pf1, vb1, o, 0, 0, 0);
            oacc[dt] = o;
        }

#pragma unroll
        for (int nt = 0; nt < 4; nt++)
#pragma unroll
            for (int r = 0; r < 4; r++) mv[nt][r] = mvn[nt][r];
    }

    // single end-of-loop butterfly over the 16 column-lanes
#pragma unroll
    for (int r = 0; r < 4; r++) {
#pragma unroll
        for (int off = 1; off < 16; off <<= 1)
            l_acc[r] += __shfl_xor(l_acc[r], off);
    }

    const int b = bh >> 4, h = bh & 15;
#pragma unroll
    for (int dt = 0; dt < 4; dt++)
#pragma unroll
        for (int r = 0; r < 4; r++) {
            const int qg = q0 + wv * 16 + q4 * 4 + r;
            const int d  = dt * 16 + l15;
            const float v = oacc[dt][r] / l_acc[r];
            ctx[((long)(b * S_ + qg)) * D_ + h * HD_ + d] = f_to_bf16bits(v);
        }
}

extern "C" void kernel_launch(void* const* d_in, const int* in_sizes, int n_in,
                              void* d_out, int out_size, void* d_ws, size_t ws_size,
                              hipStream_t stream) {
    const float* X    = (const float*)d_in[0];
    const float* mask = (const float*)d_in[1];
    const float* Wq   = (const float*)d_in[2];
    const float* Wk   = (const float*)d_in[3];
    const float* Wv   = (const float*)d_in[4];
    const float* Wo   = (const float*)d_in[5];
    float* out        = (float*)d_out;

    unsigned short* ws = (unsigned short*)d_ws;
    unsigned short* qws  = ws;                 // 4M elems each
    unsigned short* kws  = ws + 4194304;
    unsigned short* vtws = ws + 8388608;
    unsigned short* ctx  = ws + 12582912;
    unsigned short* Xb   = ws + 16777216;      // 4M
    unsigned short* Wqb  = ws + 20971520;      // 1M each
    unsigned short* Wkb  = ws + 22020096;
    unsigned short* Wvb  = ws + 23068672;
    unsigned short* Wob  = ws + 24117248;      // end = 48MB

    cvt_bf16<<<dim3(4096), 256, 0, stream>>>(X, Wq, Wk, Wv, Wo, Xb, Wqb, Wkb, Wvb, Wob);
    gemm_bt<<<dim3(32, 8, 3), 256, 0, stream>>>(Xb, Wqb, Wkb, Wvb, qws, kws, vtws, 0);
    attn<<<dim3(32, 32, 1), 256, 0, stream>>>(qws, kws, vtws, mask, ctx);
    gemm_bt<<<dim3(32, 8, 1), 256, 0, stream>>>(ctx, Wob, Wob, Wob, out, out, out, 3);
}

// Round 10
// 223.761 us; speedup vs baseline: 1.2240x; 1.0686x over previous
//
#include <hip/hip_runtime.h>

// Problem constants
#define B_  2
#define S_  2048
#define D_  1024
#define H_  16
#define HD_ 64
#define M_  (B_*S_)   // 4096

typedef __attribute__((ext_vector_type(8))) short  short8;   // 8 bf16 (4 VGPRs)
typedef __attribute__((ext_vector_type(4))) float  float4v;  // 4 fp32
typedef __attribute__((ext_vector_type(4))) int    int4v;    // 16B
typedef __attribute__((ext_vector_type(4))) unsigned short ushort4v; // 8B

// 1/sqrt(D) * log2(e): softmax via native exp2 (v_exp_f32)
#define PSCALE 0.0450843341f   // (1/32) * 1.4426950408889634

__device__ __forceinline__ unsigned int pack2_bf16(float a, float b) {
#if __has_builtin(__builtin_amdgcn_cvt_pk_bf16_f32)
    auto p = __builtin_amdgcn_cvt_pk_bf16_f32(a, b);   // 1 VALU op, RNE
    return __builtin_bit_cast(unsigned int, p);
#else
    unsigned int xa = __builtin_bit_cast(unsigned int, a);
    unsigned int xb = __builtin_bit_cast(unsigned int, b);
    xa += 0x7fffu + ((xa >> 16) & 1u);
    xb += 0x7fffu + ((xb >> 16) & 1u);
    return (xa >> 16) | (xb & 0xffff0000u);
#endif
}
__device__ __forceinline__ unsigned short f_to_bf16bits(float f) {
#if __has_builtin(__builtin_amdgcn_cvt_pk_bf16_f32)
    return (unsigned short)(pack2_bf16(f, f) & 0xffffu);
#else
    unsigned int x = __builtin_bit_cast(unsigned int, f);
    x += 0x7fffu + ((x >> 16) & 1u);
    return (unsigned short)(x >> 16);
#endif
}

__device__ __forceinline__ float fast_exp2(float x) {
#if __has_builtin(__builtin_amdgcn_exp2f)
    return __builtin_amdgcn_exp2f(x);
#else
    return exp2f(x);
#endif
}

// ---------------------------------------------------------------------------
// fp32 -> bf16 bulk convert: X(4M) + Wq,Wk,Wv,Wo (1M each). 8 elems/thread.
// ---------------------------------------------------------------------------
__global__ __launch_bounds__(256) void cvt_bf16(
    const float* __restrict__ X,  const float* __restrict__ Wq,
    const float* __restrict__ Wk, const float* __restrict__ Wv,
    const float* __restrict__ Wo,
    unsigned short* __restrict__ Xb,  unsigned short* __restrict__ Wqb,
    unsigned short* __restrict__ Wkb, unsigned short* __restrict__ Wvb,
    unsigned short* __restrict__ Wob)
{
    const long t = (long)blockIdx.x * 256 + threadIdx.x;
    const long e = t * 8;
    const float* src; unsigned short* dst; long off;
    if      (e < 4194304) { src = X;  dst = Xb;  off = e; }
    else if (e < 5242880) { src = Wq; dst = Wqb; off = e - 4194304; }
    else if (e < 6291456) { src = Wk; dst = Wkb; off = e - 5242880; }
    else if (e < 7340032) { src = Wv; dst = Wvb; off = e - 6291456; }
    else                  { src = Wo; dst = Wob; off = e - 7340032; }
    float4v a = *(const float4v*)&src[off];
    float4v b = *(const float4v*)&src[off + 4];
    int4v o;
    o[0] = (int)pack2_bf16(a[0], a[1]);
    o[1] = (int)pack2_bf16(a[2], a[3]);
    o[2] = (int)pack2_bf16(b[0], b[1]);
    o[3] = (int)pack2_bf16(b[2], b[3]);
    *(int4v*)&dst[off] = o;
}

// ---------------------------------------------------------------------------
// NT GEMM, BK=64, distance-1 register prefetch (R7 variant, best measured).
// mode 0: Q  out[((b*H+h)*S+s)*HD+hd] * PSCALE  (exp2-folded softmax scale)
// mode 1: K  same layout, unscaled
// mode 2: Vt out[((b*H+h)*HD+hd)*S+s] -- operands SWAPPED (A=Wv, B=X)
// mode 3: fp32 row-major out[m*D+n]
// ---------------------------------------------------------------------------
__global__ __launch_bounds__(256) void gemm_bt(
    const unsigned short* __restrict__ A,
    const unsigned short* __restrict__ B0,
    const unsigned short* __restrict__ B1,
    const unsigned short* __restrict__ B2,
    void* __restrict__ O0, void* __restrict__ O1, void* __restrict__ O2,
    int mode_base)
{
    const int K = 1024;
    const int z = blockIdx.z;
    const int mode = mode_base + z;
    const unsigned short* Aop;
    const unsigned short* Bop;
    void* Op = (z == 0) ? O0 : (z == 1) ? O1 : O2;
    int m0, n0;
    if (mode == 2) {            // swapped: A=Wv (rows=out-dim), B=X (rows=s)
        Aop = B2; Bop = A;
        m0 = blockIdx.y * 128;
        n0 = blockIdx.x * 128;
    } else {
        Aop = A;
        Bop = (z == 0) ? B0 : (z == 1) ? B1 : B2;
        m0 = blockIdx.x * 128;
        n0 = blockIdx.y * 128;
    }

    __shared__ alignas(16) unsigned short As[128 * 64];   // 16 KB
    __shared__ alignas(16) unsigned short Bs[128 * 64];   // 16 KB

    const int tid  = threadIdx.x;
    const int wv   = tid >> 6;
    const int lane = tid & 63;
    const int wm   = wv >> 1, wn = wv & 1;
    const int q4   = lane >> 4, l15 = lane & 15;

    const unsigned short* gA[4];
    const unsigned short* gB[4];
    int ldsoff[4];
#pragma unroll
    for (int j = 0; j < 4; j++) {
        const int r = wv * 32 + j * 8 + (lane >> 3);
        const int c = (((lane & 7) ^ (r & 7)) * 8);
        gA[j] = Aop + (long)(m0 + r) * K + c;
        gB[j] = Bop + (long)(n0 + r) * K + c;
        ldsoff[j] = (wv * 32 + j * 8) * 64 + lane * 8;   // phys chunk = lane&7
    }

    int aoff[2][4], boff[2][4];
#pragma unroll
    for (int ks = 0; ks < 2; ks++)
#pragma unroll
        for (int t = 0; t < 4; t++) {
            const int swz = (((ks * 4 + q4) ^ (l15 & 7)) * 8);
            aoff[ks][t] = (wm * 64 + t * 16 + l15) * 64 + swz;
            boff[ks][t] = (wn * 64 + t * 16 + l15) * 64 + swz;
        }

    float4v acc[4][4];
#pragma unroll
    for (int i = 0; i < 4; i++)
#pragma unroll
        for (int j = 0; j < 4; j++) acc[i][j] = (float4v)0.0f;

    int4v ar[4], br[4];
#pragma unroll
    for (int j = 0; j < 4; j++) {
        ar[j] = *(const int4v*)gA[j];
        br[j] = *(const int4v*)gB[j];
        gA[j] += 64; gB[j] += 64;
    }

    for (int k0 = 0; k0 < K; k0 += 64) {
        __syncthreads();
#pragma unroll
        for (int j = 0; j < 4; j++) {
            *(int4v*)&As[ldsoff[j]] = ar[j];
            *(int4v*)&Bs[ldsoff[j]] = br[j];
        }
        __syncthreads();

        if (k0 + 64 < K) {
#pragma unroll
            for (int j = 0; j < 4; j++) {
                ar[j] = *(const int4v*)gA[j];
                br[j] = *(const int4v*)gB[j];
                gA[j] += 64; gB[j] += 64;
            }
        }

#pragma unroll
        for (int ks = 0; ks < 2; ks++) {
            short8 afr[4], bfr[4];
#pragma unroll
            for (int mt = 0; mt < 4; mt++) afr[mt] = *(const short8*)&As[aoff[ks][mt]];
#pragma unroll
            for (int nt = 0; nt < 4; nt++) bfr[nt] = *(const short8*)&Bs[boff[ks][nt]];
#pragma unroll
            for (int mt = 0; mt < 4; mt++)
#pragma unroll
                for (int nt = 0; nt < 4; nt++)
                    acc[mt][nt] = __builtin_amdgcn_mfma_f32_16x16x32_bf16(
                        afr[mt], bfr[nt], acc[mt][nt], 0, 0, 0);
        }
    }

#pragma unroll
    for (int mt = 0; mt < 4; mt++)
#pragma unroll
        for (int nt = 0; nt < 4; nt++)
#pragma unroll
            for (int r = 0; r < 4; r++) {
                const int m = m0 + wm * 64 + mt * 16 + q4 * 4 + r;
                const int n = n0 + wn * 64 + nt * 16 + l15;
                float v = acc[mt][nt][r];
                if (mode == 3) {
                    ((float*)Op)[(long)m * D_ + n] = v;
                } else if (mode == 2) {
                    const long off = (((long)(n >> 11) * H_ + (m >> 6)) * HD_ + (m & 63)) * S_ + (n & 2047);
                    ((unsigned short*)Op)[off] = f_to_bf16bits(v);
                } else {
                    const long off = ((long)((m >> 11) * H_ + (n >> 6)) * S_ + (m & 2047)) * HD_ + (n & 63);
                    if (mode == 0) v *= PSCALE;
                    ((unsigned short*)Op)[off] = f_to_bf16bits(v);
                }
            }
}

// ---------------------------------------------------------------------------
// Flash attention, LDS-traffic-optimized: 2 waves / 128 thr per WG; each
// wave owns 32 q-rows (2 m-tiles) so every K/V fragment read feeds TWO
// MFMAs (was one) -- LDS read bytes per MFMA halve. WG = 64 q-rows; grid
// 32 q-blocks x 32 bh = 1024 WGs (4 WG/CU). Padded x72 LDS layout (R3-
// proven), in-loop staging, exp2 softmax (PSCALE pre-folded into Q), no
// online-max (scores bounded; normalization divides out constants).
// ---------------------------------------------------------------------------
__global__ __launch_bounds__(128) void attn(
    const unsigned short* __restrict__ Q,    // [B,H,S,HD], pre-scaled by PSCALE
    const unsigned short* __restrict__ Kk,   // [B,H,S,HD]
    const unsigned short* __restrict__ Vt,   // [B,H,HD,S]
    const float* __restrict__ mask,          // [S,S]
    unsigned short* __restrict__ ctx)        // [B,S,D]
{
    __shared__ alignas(16) unsigned short Ks [64 * 72];      // [k_local][d]   9 KB
    __shared__ alignas(16) unsigned short Vts[64 * 72];      // [d][k_local]   9 KB
    __shared__ alignas(16) unsigned short Ps [2][32 * 72];   // per-wave P     9 KB

    const int tid  = threadIdx.x;      // 0..127
    const int wv   = tid >> 6;         // 0..1
    const int lane = tid & 63;
    const int q4   = lane >> 4, l15 = lane & 15;
    const int bh   = blockIdx.y;
    const int q0   = blockIdx.x * 64;

    const long head = (long)bh * S_ * HD_;

    // Q fragments: wave covers rows q0 + wv*32 + mt*16 + l15, mt = 0,1
    short8 qfr[2][2];
#pragma unroll
    for (int mt = 0; mt < 2; mt++) {
        const int qrow = q0 + wv * 32 + mt * 16 + l15;
        qfr[mt][0] = *(const short8*)&Q[head + (long)qrow * HD_ + q4 * 8];
        qfr[mt][1] = *(const short8*)&Q[head + (long)qrow * HD_ + 32 + q4 * 8];
    }

    float l_acc[2][4];
#pragma unroll
    for (int mt = 0; mt < 2; mt++)
#pragma unroll
        for (int r = 0; r < 4; r++) l_acc[mt][r] = 0.0f;
    float4v oacc[2][4];
#pragma unroll
    for (int mt = 0; mt < 2; mt++)
#pragma unroll
        for (int dt = 0; dt < 4; dt++) oacc[mt][dt] = (float4v)0.0f;

    // staging: 128 thr, K tile 64x64 + V tile 64x64, 4 x 16B each per matrix;
    // load j covers rows j*16 + tid/8; col (tid&7)*8
    const int srow = tid >> 3;         // 0..15
    const int scol = (tid & 7) * 8;    // 0..56
    const unsigned short* gK[4];
    const unsigned short* gV[4];
    int ldsOff[4];
#pragma unroll
    for (int j = 0; j < 4; j++) {
        const int row = j * 16 + srow;
        gK[j] = Kk + head + (long)row * HD_ + scol;
        gV[j] = Vt + head + (long)row * S_  + scol;
        ldsOff[j] = row * 72 + scol;
    }

    // per-thread mask row bases
    const float* mrow[2][4];
#pragma unroll
    for (int mt = 0; mt < 2; mt++)
#pragma unroll
        for (int r = 0; r < 4; r++)
            mrow[mt][r] = mask + (long)(q0 + wv * 32 + mt * 16 + q4 * 4 + r) * S_ + l15;

    for (int k0 = 0; k0 < S_; k0 += 64) {
        __syncthreads();   // prior iter's LDS reads done (WAR)
#pragma unroll
        for (int j = 0; j < 4; j++) {
            *(int4v*)&Ks [ldsOff[j]] = *(const int4v*)(gK[j] + (long)k0 * HD_);
            *(int4v*)&Vts[ldsOff[j]] = *(const int4v*)(gV[j] + k0);
        }
        __syncthreads();

        // mask loads issued first (L2-hot): latency hidden under QK below
        float mv[2][4][4];
#pragma unroll
        for (int mt = 0; mt < 2; mt++)
#pragma unroll
            for (int nt = 0; nt < 4; nt++)
#pragma unroll
                for (int r = 0; r < 4; r++)
                    mv[mt][nt][r] = mrow[mt][r][k0 + nt * 16];

        // QK^T: each kb pair feeds both m-tiles (2 MFMAs per ds_read pair)
        float4v sfr[2][4];
#pragma unroll
        for (int nt = 0; nt < 4; nt++) {
            short8 kb0 = *(const short8*)&Ks[(nt * 16 + l15) * 72 + q4 * 8];
            short8 kb1 = *(const short8*)&Ks[(nt * 16 + l15) * 72 + 32 + q4 * 8];
#pragma unroll
            for (int mt = 0; mt < 2; mt++) {
                float4v s = (float4v)0.0f;
                s = __builtin_amdgcn_mfma_f32_16x16x32_bf16(qfr[mt][0], kb0, s, 0, 0, 0);
                s = __builtin_amdgcn_mfma_f32_16x16x32_bf16(qfr[mt][1], kb1, s, 0, 0, 0);
                sfr[mt][nt] = s;
            }
        }

        // p = 2^(dot_scaled + mask*PSCALE); per-lane row sums; P -> LDS
#pragma unroll
        for (int mt = 0; mt < 2; mt++)
#pragma unroll
            for (int nt = 0; nt < 4; nt++)
#pragma unroll
                for (int r = 0; r < 4; r++) {
                    const float p = fast_exp2(fmaf(mv[mt][nt][r], PSCALE, sfr[mt][nt][r]));
                    l_acc[mt][r] += p;
                    Ps[wv][(mt * 16 + q4 * 4 + r) * 72 + nt * 16 + l15] = f_to_bf16bits(p);
                }

        // P fragments (A-layout), per m-tile
        short8 pf[2][2];
#pragma unroll
        for (int mt = 0; mt < 2; mt++) {
            pf[mt][0] = *(const short8*)&Ps[wv][(mt * 16 + l15) * 72 + q4 * 8];
            pf[mt][1] = *(const short8*)&Ps[wv][(mt * 16 + l15) * 72 + 32 + q4 * 8];
        }

        // O += P V: each vb pair feeds both m-tiles
#pragma unroll
        for (int dt = 0; dt < 4; dt++) {
            short8 vb0 = *(const short8*)&Vts[(dt * 16 + l15) * 72 + q4 * 8];
            short8 vb1 = *(const short8*)&Vts[(dt * 16 + l15) * 72 + 32 + q4 * 8];
#pragma unroll
            for (int mt = 0; mt < 2; mt++) {
                float4v o = oacc[mt][dt];
                o = __builtin_amdgcn_mfma_f32_16x16x32_bf16(pf[mt][0], vb0, o, 0, 0, 0);
                o = __builtin_amdgcn_mfma_f32_16x16x32_bf16(pf[mt][1], vb1, o, 0, 0, 0);
                oacc[mt][dt] = o;
            }
        }
    }

    // single end-of-loop butterfly over the 16 column-lanes
#pragma unroll
    for (int mt = 0; mt < 2; mt++)
#pragma unroll
        for (int r = 0; r < 4; r++) {
#pragma unroll
            for (int off = 1; off < 16; off <<= 1)
                l_acc[mt][r] += __shfl_xor(l_acc[mt][r], off);
        }

    const int b = bh >> 4, h = bh & 15;
#pragma unroll
    for (int mt = 0; mt < 2; mt++)
#pragma unroll
        for (int dt = 0; dt < 4; dt++)
#pragma unroll
            for (int r = 0; r < 4; r++) {
                const int qg = q0 + wv * 32 + mt * 16 + q4 * 4 + r;
                const int d  = dt * 16 + l15;
                const float v = oacc[mt][dt][r] / l_acc[mt][r];
                ctx[((long)(b * S_ + qg)) * D_ + h * HD_ + d] = f_to_bf16bits(v);
            }
}

extern "C" void kernel_launch(void* const* d_in, const int* in_sizes, int n_in,
                              void* d_out, int out_size, void* d_ws, size_t ws_size,
                              hipStream_t stream) {
    const float* X    = (const float*)d_in[0];
    const float* mask = (const float*)d_in[1];
    const float* Wq   = (const float*)d_in[2];
    const float* Wk   = (const float*)d_in[3];
    const float* Wv   = (const float*)d_in[4];
    const float* Wo   = (const float*)d_in[5];
    float* out        = (float*)d_out;

    unsigned short* ws = (unsigned short*)d_ws;
    unsigned short* qws  = ws;                 // 4M elems each
    unsigned short* kws  = ws + 4194304;
    unsigned short* vtws = ws + 8388608;
    unsigned short* ctx  = ws + 12582912;
    unsigned short* Xb   = ws + 16777216;      // 4M
    unsigned short* Wqb  = ws + 20971520;      // 1M each
    unsigned short* Wkb  = ws + 22020096;
    unsigned short* Wvb  = ws + 23068672;
    unsigned short* Wob  = ws + 24117248;      // end = 48MB

    cvt_bf16<<<dim3(4096), 256, 0, stream>>>(X, Wq, Wk, Wv, Wo, Xb, Wqb, Wkb, Wvb, Wob);
    gemm_bt<<<dim3(32, 8, 3), 256, 0, stream>>>(Xb, Wqb, Wkb, Wvb, qws, kws, vtws, 0);
    attn<<<dim3(32, 32, 1), 128, 0, stream>>>(qws, kws, vtws, mask, ctx);
    gemm_bt<<<dim3(32, 8, 1), 256, 0, stream>>>(ctx, Wob, Wob, Wob, out, out, out, 3);
}